// Round 12
// baseline (975.156 us; speedup 1.0000x reference)
//
#include <hip/hip_runtime.h>
#include <cstdint>
#include <cstddef>

constexpr int kB   = 64;
constexpr int kNPG = 48;
constexpr int kN   = 6144;
constexpr int kE   = 147456;
constexpr int kE2  = 294912;
constexpr int kEG  = 98304;
constexpr int kH   = 128;
constexpr int kHT  = 64;
constexpr int kL   = 3;

using short8 = __attribute__((ext_vector_type(8))) short;
using f32x4  = __attribute__((ext_vector_type(4))) float;

__device__ __forceinline__ unsigned short f2bf(float x) {
    unsigned int u = __float_as_uint(x);
    u = (u + 0x7FFFu + ((u >> 16) & 1u)) >> 16;   // RNE
    return (unsigned short)u;
}
__device__ __forceinline__ float bf2f(unsigned short v) {
    return __uint_as_float(((unsigned int)v) << 16);
}
// split-bf16 pack: hi = truncated top-16, lo = RNE(residual). hi+lo carries
// ~2^-16 relative precision; only the SUM matters (both halves feed f32 MFMA acc).
__device__ __forceinline__ uint32_t packsplit(float v) {
    unsigned int u = __float_as_uint(v);
    unsigned int hi = u >> 16;
    float vhi = __uint_as_float(u & 0xffff0000u);
    unsigned short lo = f2bf(v - vhi);            // exact residual, RNE to bf16
    return hi | ((uint32_t)lo << 16);
}
__device__ __forceinline__ f32x4 mfma16(short8 a, short8 b, f32x4 c) {
    return __builtin_amdgcn_mfma_f32_16x16x32_bf16(a, b, c, 0, 0, 0);
}
__device__ __forceinline__ void loadfrag(const uint32_t* p, short8& hi, short8& lo) {
    uint4 q0 = *(const uint4*)p;
    uint4 q1 = *(const uint4*)(p + 4);
    uint32_t qs[8] = {q0.x, q0.y, q0.z, q0.w, q1.x, q1.y, q1.z, q1.w};
    #pragma unroll
    for (int j = 0; j < 8; ++j) { hi[j] = (short)(qs[j] & 0xffff); lo[j] = (short)(qs[j] >> 16); }
}

// ---------------- weight prep: f32 [K][N] -> bf16 MFMA-B-fragment order ----------
__global__ void k_wprep(const float* __restrict__ W, unsigned short* __restrict__ Wf, int N) {
    int lane = threadIdx.x;                 // 64
    int NT = N >> 4;
    int kt = blockIdx.x / NT, nt = blockIdx.x % NT;
    int k0 = kt * 32 + (lane >> 4) * 8;
    int col = nt * 16 + (lane & 15);
    unsigned short tmp[8];
    #pragma unroll
    for (int j = 0; j < 8; ++j) tmp[j] = f2bf(W[(size_t)(k0 + j) * N + col]);
    unsigned short* dst = Wf + (((size_t)blockIdx.x) * 64 + lane) * 8;
    *(uint4*)dst = *(const uint4*)tmp;
}

struct WSrcs { const float* p[22]; };
__global__ void k_wprep_multi(WSrcs s, unsigned short* __restrict__ Wf) {
    int lane = threadIdx.x;
    int mat = blockIdx.x >> 5, tile = blockIdx.x & 31;
    int kt = tile >> 3, nt = tile & 7;
    const float* W = s.p[mat];
    int k0 = kt * 32 + (lane >> 4) * 8;
    int col = nt * 16 + (lane & 15);
    unsigned short tmp[8];
    #pragma unroll
    for (int j = 0; j < 8; ++j) tmp[j] = f2bf(W[(size_t)(k0 + j) * kH + col]);
    unsigned short* dst = Wf + (size_t)mat * 16384 + (((size_t)tile) * 64 + lane) * 8;
    *(uint4*)dst = *(const uint4*)tmp;
}

// ---------------- PE gemm: e0 = PE(attr) @ ew + eb. Rows j and kE+j are
// IDENTICAL (same attr, same weights) -> compute once, store both halves.
__global__ __launch_bounds__(256) void k_pegemm(const float* __restrict__ attr,
                                                const unsigned short* __restrict__ wf,
                                                const float* __restrict__ eb,
                                                uint32_t* __restrict__ e_packed) {
    int t = threadIdx.x, lane = t & 63, w = t >> 6;
    int rowbase = blockIdx.x * 64 + w * 16;       // < kE
    float av = attr[rowbase + (lane & 15)];
    f32x4 acc[8];
    #pragma unroll
    for (int nt = 0; nt < 8; ++nt) acc[nt] = (f32x4){0.f, 0.f, 0.f, 0.f};
    #pragma unroll
    for (int kt = 0; kt < 4; ++kt) {
        short8 ahi, alo;
        int k0 = kt * 32 + (lane >> 4) * 8;
        #pragma unroll
        for (int j = 0; j < 8; ++j) {
            int k = k0 + j;
            float freq = exp2f(-(float)(k >> 1) * 0.20762050593046264f); // 2*log2(1e4)/128
            float ang = av * freq;
            float v = (k & 1) ? __cosf(ang) : __sinf(ang);
            unsigned short h = f2bf(v);
            unsigned short l2 = f2bf(v - bf2f(h));
            ahi[j] = (short)h; alo[j] = (short)l2;
        }
        #pragma unroll
        for (int nt = 0; nt < 8; ++nt) {
            short8 wb = *(const short8*)&wf[(((size_t)kt * 8 + nt) * 64 + lane) * 8];
            acc[nt] = mfma16(ahi, wb, acc[nt]);
            acc[nt] = mfma16(alo, wb, acc[nt]);
        }
    }
    #pragma unroll
    for (int nt = 0; nt < 8; ++nt) {
        int col = nt * 16 + (lane & 15);
        float bb = eb[col];
        #pragma unroll
        for (int reg = 0; reg < 4; ++reg) {
            int row = rowbase + (lane >> 4) * 4 + reg;
            uint32_t pk = packsplit(acc[nt][reg] + bb);
            e_packed[(size_t)row * kH + col] = pk;
            e_packed[(size_t)(row + kE) * kH + col] = pk;
        }
    }
}

// ---------------- fused node kernel: gin -> MLP -> GraphNorm -> 4 projections ----
// block = one half-graph (48 nodes). NO h-fold (k_agg owns the h update).
__global__ __launch_bounds__(256) void k_node(
    float* __restrict__ h,
    int l, const int* __restrict__ rs, const int* __restrict__ csr,
    const float* __restrict__ gin_eps,
    const unsigned short* __restrict__ wf_g1, const float* __restrict__ b1,
    const unsigned short* __restrict__ wf_g2, const float* __restrict__ b2,
    const float* __restrict__ gnw, const float* __restrict__ gnb, const float* __restrict__ gnms,
    const unsigned short* __restrict__ wf_B, const float* __restrict__ Bb,
    const unsigned short* __restrict__ wf_C, const float* __restrict__ Cb,
    const unsigned short* __restrict__ wf_V, const float* __restrict__ Vb,
    const unsigned short* __restrict__ wf_U, const float* __restrict__ Ub,
    float* __restrict__ hB, float* __restrict__ hC, float* __restrict__ hV, float* __restrict__ hU)
{
    __shared__ char sA[48 * 132 * 4];   // hS (f32) -> m1pk (u32) -> hnpk (u32)
    __shared__ char sB[48 * 132 * 4];   // zpk (u32) -> z2S (f32)
    __shared__ float mmS[128], aS[128], red0[128], red1[128];
    float    (*hS)[132]   = (float(*)[132])sA;
    uint32_t (*m1pk)[132] = (uint32_t(*)[132])sA;
    uint32_t (*hnpk)[132] = (uint32_t(*)[132])sA;
    uint32_t (*zpk)[132]  = (uint32_t(*)[132])sB;
    float    (*z2S)[132]  = (float(*)[132])sB;
    int t = threadIdx.x, lane = t & 63, w = t >> 6;
    int g = blockIdx.x, nbase = g * 48;

    // P0: load h
    for (int i = t; i < 48 * 128; i += 256) {
        int r = i >> 7, c = i & 127;
        hS[r][c] = h[(size_t)(nbase + r) * kH + c];
    }
    __syncthreads();

    // P1: GIN gather z = (1+eps)h + sum_neigh h  (neighbors are block-local)
    {
        float eps1 = 1.f + gin_eps[l];
        int c = t & 127;
        for (int rp = t >> 7; rp < 48; rp += 2) {
            float acc = eps1 * hS[rp][c];
            int s0 = rs[nbase + rp], s1 = rs[nbase + rp + 1];
            for (int k = s0; k < s1; ++k) {
                int s = csr[k] - nbase;
                acc += hS[s][c];
            }
            zpk[rp][c] = packsplit(acc);
        }
    }
    __syncthreads();

    // P2: GEMM1 z@W1 -> relu -> m1 (split-bf16, alias sA)
    {
        f32x4 acc1[8];
        if (w < 3) {
            #pragma unroll
            for (int nt = 0; nt < 8; ++nt) acc1[nt] = (f32x4){0.f, 0.f, 0.f, 0.f};
            #pragma unroll
            for (int kt = 0; kt < 4; ++kt) {
                short8 hi, lo;
                loadfrag(&zpk[w * 16 + (lane & 15)][kt * 32 + (lane >> 4) * 8], hi, lo);
                #pragma unroll
                for (int nt = 0; nt < 8; ++nt) {
                    short8 wb = *(const short8*)&wf_g1[(((size_t)kt * 8 + nt) * 64 + lane) * 8];
                    acc1[nt] = mfma16(hi, wb, acc1[nt]);
                    acc1[nt] = mfma16(lo, wb, acc1[nt]);
                }
            }
        }
        __syncthreads();   // hS dead -> safe to write m1pk
        if (w < 3) {
            #pragma unroll
            for (int nt = 0; nt < 8; ++nt) {
                int col = nt * 16 + (lane & 15);
                float bb = b1[col];
                #pragma unroll
                for (int reg = 0; reg < 4; ++reg) {
                    int row = w * 16 + (lane >> 4) * 4 + reg;
                    m1pk[row][col] = packsplit(fmaxf(acc1[nt][reg] + bb, 0.f));
                }
            }
        }
    }
    __syncthreads();

    // P3: GEMM2 m1@W2 -> z2 (f32, alias sB)
    {
        f32x4 acc2[8];
        if (w < 3) {
            #pragma unroll
            for (int nt = 0; nt < 8; ++nt) acc2[nt] = (f32x4){0.f, 0.f, 0.f, 0.f};
            #pragma unroll
            for (int kt = 0; kt < 4; ++kt) {
                short8 hi, lo;
                loadfrag(&m1pk[w * 16 + (lane & 15)][kt * 32 + (lane >> 4) * 8], hi, lo);
                #pragma unroll
                for (int nt = 0; nt < 8; ++nt) {
                    short8 wb = *(const short8*)&wf_g2[(((size_t)kt * 8 + nt) * 64 + lane) * 8];
                    acc2[nt] = mfma16(hi, wb, acc2[nt]);
                    acc2[nt] = mfma16(lo, wb, acc2[nt]);
                }
            }
        }
        __syncthreads();   // zpk dead
        if (w < 3) {
            #pragma unroll
            for (int nt = 0; nt < 8; ++nt) {
                int col = nt * 16 + (lane & 15);
                float bb = b2[col];
                #pragma unroll
                for (int reg = 0; reg < 4; ++reg) {
                    int row = w * 16 + (lane >> 4) * 4 + reg;
                    z2S[row][col] = acc2[nt][reg] + bb;
                }
            }
        }
    }
    __syncthreads();

    // P4: GraphNorm stats over the 48 rows
    {
        int c = t & 127, hh = t >> 7;
        float s = 0.f;
        for (int r = hh * 24; r < hh * 24 + 24; ++r) s += z2S[r][c];
        if (hh == 0) red0[c] = s; else red1[c] = s;
        __syncthreads();
        if (t < 128) {
            float mean = (red0[t] + red1[t]) * (1.f / 48.f);
            mmS[t] = mean * gnms[t];
        }
        __syncthreads();
        float mm = mmS[c];
        float s2 = 0.f;
        for (int r = hh * 24; r < hh * 24 + 24; ++r) { float d = z2S[r][c] - mm; s2 = fmaf(d, d, s2); }
        if (hh == 0) red0[c] = s2; else red1[c] = s2;
        __syncthreads();
        if (t < 128) {
            float var = (red0[t] + red1[t]) * (1.f / 48.f);
            aS[t] = gnw[t] * rsqrtf(var + 1e-5f);
        }
    }
    __syncthreads();

    // P5: h_new = relu(a*(z2-mm)+gnb) -> global h + split-bf16 pack (alias sA)
    for (int i = t; i < 48 * 128; i += 256) {
        int r = i >> 7, c = i & 127;
        float hn = fmaxf(aS[c] * (z2S[r][c] - mmS[c]) + gnb[c], 0.f);
        h[(size_t)(nbase + r) * kH + c] = hn;
        hnpk[r][c] = packsplit(hn);
    }
    __syncthreads();

    // P6: projections hB,hC,hV,hU = h_new @ {B,C,V,U} + bias
    {
        const unsigned short* wfs[4] = {wf_B, wf_C, wf_V, wf_U};
        const float* bs[4] = {Bb, Cb, Vb, Ub};
        float* outs[4] = {hB, hC, hV, hU};
        #pragma unroll 4
        for (int m = 0; m < 4; ++m) {
            if (w < 3) {
                f32x4 accp[8];
                #pragma unroll
                for (int nt = 0; nt < 8; ++nt) accp[nt] = (f32x4){0.f, 0.f, 0.f, 0.f};
                #pragma unroll
                for (int kt = 0; kt < 4; ++kt) {
                    short8 hi, lo;
                    loadfrag(&hnpk[w * 16 + (lane & 15)][kt * 32 + (lane >> 4) * 8], hi, lo);
                    #pragma unroll
                    for (int nt = 0; nt < 8; ++nt) {
                        short8 wb = *(const short8*)&wfs[m][(((size_t)kt * 8 + nt) * 64 + lane) * 8];
                        accp[nt] = mfma16(hi, wb, accp[nt]);
                        accp[nt] = mfma16(lo, wb, accp[nt]);
                    }
                }
                #pragma unroll
                for (int nt = 0; nt < 8; ++nt) {
                    int col = nt * 16 + (lane & 15);
                    float bb = bs[m][col];
                    #pragma unroll
                    for (int reg = 0; reg < 4; ++reg) {
                        int row = w * 16 + (lane >> 4) * 4 + reg;
                        outs[m][(size_t)(nbase + row) * kH + col] = accp[nt][reg] + bb;
                    }
                }
            }
        }
    }
}

// ---------------- AGNN edge gemm (padded LDS, gate store templated) --------------
// e_new = e@A + Ab + hB[src]+hC[dst]+tG[p]; gate=sigmoid (bf16); e += relu(e_new).
template<bool GATE>
__global__ __launch_bounds__(256) void k_egemm(uint32_t* __restrict__ e_packed,
                                               const unsigned short* __restrict__ wfA,
                                               const float* __restrict__ Ab,
                                               const float* __restrict__ tGl,
                                               const float* __restrict__ hB,
                                               const float* __restrict__ hC,
                                               unsigned short* __restrict__ gate) {
    __shared__ float X[48][132];   // b-side node rows (+4 pad: kill 4-way bank conflict)
    __shared__ float Y[4][132];    // a-side node rows
    __shared__ float Z[128];       // tG[p] + Ab
    int t = threadIdx.x, lane = t & 63, w = t >> 6;
    int row0 = blockIdx.x * 128;
    int half = row0 >= kE;
    int off = row0 - (half ? kE : 0);
    int p = off / 2304;
    int off2 = off - p * 2304;
    int a0 = off2 / 48, boff = off2 - a0 * 48;
    const float* Xsrc = half ? hB : hC;
    const float* Ysrc = half ? hC : hB;

    if (t < 128) Z[t] = tGl[p * kH + t] + Ab[t];
    for (int i = t; i < 48 * 32; i += 256) {
        int r = i >> 5, c = (i & 31) << 2;
        *(float4*)&X[r][c] = *(const float4*)&Xsrc[(size_t)(p * 96 + 48 + r) * kH + c];
    }
    for (int i = t; i < 4 * 32; i += 256) {
        int r = i >> 5, c = (i & 31) << 2;
        int a = a0 + r; if (a > 47) a = 47;
        *(float4*)&Y[r][c] = *(const float4*)&Ysrc[(size_t)(p * 96 + a) * kH + c];
    }
    __syncthreads();

    f32x4 acc[2][8];
    #pragma unroll
    for (int rt = 0; rt < 2; ++rt)
        #pragma unroll
        for (int nt = 0; nt < 8; ++nt) acc[rt][nt] = (f32x4){0.f, 0.f, 0.f, 0.f};

    #pragma unroll
    for (int kt = 0; kt < 4; ++kt) {
        short8 hi[2], lo[2];
        #pragma unroll
        for (int rt = 0; rt < 2; ++rt) {
            int row = row0 + w * 32 + rt * 16 + (lane & 15);
            loadfrag(e_packed + (size_t)row * kH + kt * 32 + (lane >> 4) * 8, hi[rt], lo[rt]);
        }
        #pragma unroll
        for (int nt = 0; nt < 8; ++nt) {
            short8 wb = *(const short8*)&wfA[(((size_t)kt * 8 + nt) * 64 + lane) * 8];
            #pragma unroll
            for (int rt = 0; rt < 2; ++rt) {
                acc[rt][nt] = mfma16(hi[rt], wb, acc[rt][nt]);
                acc[rt][nt] = mfma16(lo[rt], wb, acc[rt][nt]);
            }
        }
    }

    #pragma unroll
    for (int rt = 0; rt < 2; ++rt) {
        #pragma unroll
        for (int nt = 0; nt < 8; ++nt) {
            int col = nt * 16 + (lane & 15);
            float zc = Z[col];
            #pragma unroll
            for (int reg = 0; reg < 4; ++reg) {
                int rl = w * 32 + rt * 16 + (lane >> 4) * 4 + reg;   // 0..127
                int idx2 = boff + rl;
                int arel = (idx2 >= 144) ? 3 : (idx2 >= 96) ? 2 : (idx2 >= 48) ? 1 : 0;
                int b = idx2 - arel * 48;
                float v = acc[rt][nt][reg] + zc + Y[arel][col] + X[b][col];
                int grow = row0 + rl;
                if (GATE) {
                    float g = 1.f / (1.f + __expf(-v));
                    gate[(size_t)grow * kH + col] = f2bf(g);
                }
                uint32_t old = e_packed[(size_t)grow * kH + col];
                float ne = bf2f((unsigned short)(old & 0xffff)) + bf2f((unsigned short)(old >> 16))
                           + fmaxf(v, 0.f);
                e_packed[(size_t)grow * kH + col] = packsplit(ne);
            }
        }
    }
}

// ---------------- dense gated aggregation + node update (validated round-4) ------
__global__ void k_agg(const unsigned short* __restrict__ gate, const float* __restrict__ hV,
                      const float* __restrict__ hU, float* __restrict__ h) {
    int n = blockIdx.x, c = threadIdx.x;
    int p = n / 96, r = n - (n / 96) * 96;
    float acc = 0.f;
    if (r >= 48) {
        int b = r - 48;
        size_t ebase = (size_t)p * 2304 + b;
        for (int a = 0; a < 48; ++a) {
            size_t eidx = ebase + (size_t)a * 48;
            int src = p * 96 + a;
            acc = fmaf(bf2f(gate[eidx * kH + c]), hV[(size_t)src * kH + c], acc);
        }
    } else {
        int a = r;
        size_t ebase = (size_t)kE + (size_t)p * 2304 + (size_t)a * 48;
        for (int b = 0; b < 48; ++b) {
            int src = p * 96 + 48 + b;
            acc = fmaf(bf2f(gate[(ebase + b) * kH + c]), hV[(size_t)src * kH + c], acc);
        }
    }
    float v = hU[(size_t)n * kH + c] + acc;
    h[(size_t)n * kH + c] += fmaxf(v, 0.f);
}

// ---------------- fused readout (both halves per block) + final add --------------
// out[r] = partial(r) + partial(r+kE), each partial includes +mb3.
__global__ __launch_bounds__(256) void k_readout2(const uint32_t* __restrict__ e_packed,
                                                  const unsigned short* __restrict__ wf1,
                                                  const float* __restrict__ mb1,
                                                  const unsigned short* __restrict__ wf2,
                                                  const float* __restrict__ mb2,
                                                  const float* __restrict__ mw3,
                                                  const float* __restrict__ mb3,
                                                  float* __restrict__ out) {
    __shared__ char smem[64 * 528];   // aliased: eS[64][132] u32  /  m1S[64][264] bf16
    uint32_t (*eS)[132] = (uint32_t(*)[132])smem;
    unsigned short (*m1S)[264] = (unsigned short(*)[264])smem;
    int t = threadIdx.x, lane = t & 63, w = t >> 6;
    int row0 = blockIdx.x * 64;       // < kE
    float sfirst[4];

    for (int hp = 0; hp < 2; ++hp) {
        size_t rbase = (size_t)row0 + (hp ? (size_t)kE : 0);
        if (hp) __syncthreads();      // m1S reads of pass 0 done before restaging eS
        for (int i = t; i < 64 * 32; i += 256) {
            int r = i >> 5, c = (i & 31) << 2;
            *(uint4*)&eS[r][c] = *(const uint4*)&e_packed[(rbase + r) * kH + c];
        }
        __syncthreads();

        f32x4 acc1[4][4];
        #pragma unroll
        for (int rt = 0; rt < 4; ++rt)
            #pragma unroll
            for (int n = 0; n < 4; ++n) acc1[rt][n] = (f32x4){0.f, 0.f, 0.f, 0.f};
        #pragma unroll
        for (int kt = 0; kt < 4; ++kt) {
            short8 ahi[4], alo[4];
            #pragma unroll
            for (int rt = 0; rt < 4; ++rt)
                loadfrag(&eS[rt * 16 + (lane & 15)][kt * 32 + (lane >> 4) * 8], ahi[rt], alo[rt]);
            #pragma unroll
            for (int n = 0; n < 4; ++n) {
                int nt = w * 4 + n;
                short8 wb = *(const short8*)&wf1[(((size_t)kt * 16 + nt) * 64 + lane) * 8];
                #pragma unroll
                for (int rt = 0; rt < 4; ++rt) {
                    acc1[rt][n] = mfma16(ahi[rt], wb, acc1[rt][n]);
                    acc1[rt][n] = mfma16(alo[rt], wb, acc1[rt][n]);
                }
            }
        }
        __syncthreads();   // eS reads done before aliased m1S writes
        #pragma unroll
        for (int rt = 0; rt < 4; ++rt) {
            #pragma unroll
            for (int n = 0; n < 4; ++n) {
                int col = (w * 4 + n) * 16 + (lane & 15);
                float bb = mb1[col];
                #pragma unroll
                for (int reg = 0; reg < 4; ++reg) {
                    int r = rt * 16 + (lane >> 4) * 4 + reg;
                    m1S[r][col] = f2bf(fmaxf(acc1[rt][n][reg] + bb, 0.f));
                }
            }
        }
        __syncthreads();

        f32x4 acc2[8];
        #pragma unroll
        for (int nt = 0; nt < 8; ++nt) acc2[nt] = (f32x4){0.f, 0.f, 0.f, 0.f};
        #pragma unroll
        for (int kt = 0; kt < 8; ++kt) {
            int r = w * 16 + (lane & 15);
            short8 a2 = *(const short8*)&m1S[r][kt * 32 + (lane >> 4) * 8];
            #pragma unroll
            for (int nt = 0; nt < 8; ++nt) {
                short8 wb = *(const short8*)&wf2[(((size_t)kt * 8 + nt) * 64 + lane) * 8];
                acc2[nt] = mfma16(a2, wb, acc2[nt]);
            }
        }
        float s[4] = {0.f, 0.f, 0.f, 0.f};
        #pragma unroll
        for (int nt = 0; nt < 8; ++nt) {
            int col = nt * 16 + (lane & 15);
            float w3 = mw3[col], bb = mb2[col];
            #pragma unroll
            for (int reg = 0; reg < 4; ++reg)
                s[reg] += fmaxf(acc2[nt][reg] + bb, 0.f) * w3;
        }
        #pragma unroll
        for (int mask = 1; mask <= 8; mask <<= 1)
            #pragma unroll
            for (int reg = 0; reg < 4; ++reg) s[reg] += __shfl_xor(s[reg], mask);
        float b3 = mb3[0];
        if (hp == 0) {
            #pragma unroll
            for (int reg = 0; reg < 4; ++reg) sfirst[reg] = s[reg] + b3;
        } else if ((lane & 15) == 0) {
            #pragma unroll
            for (int reg = 0; reg < 4; ++reg)
                out[row0 + w * 16 + (lane >> 4) * 4 + reg] = sfirst[reg] + s[reg] + b3;
        }
    }
}

// ---------------- graph-structure + small kernels (validated) --------------------
__global__ void k_hist(const int* __restrict__ gdst, int* __restrict__ cnt) {
    int i = blockIdx.x * 256 + threadIdx.x;
    atomicAdd(&cnt[gdst[i]], 1);
}
__global__ void k_scan(const int* __restrict__ cnt, int* __restrict__ rs) {
    __shared__ int part[256];
    int t = threadIdx.x;
    const int per = kN / 256;
    int s = 0;
    for (int i = 0; i < per; ++i) s += cnt[t * per + i];
    part[t] = s;
    __syncthreads();
    if (t == 0) {
        int run = 0;
        for (int i = 0; i < 256; ++i) { int v = part[i]; part[i] = run; run += v; }
        rs[kN] = run;
    }
    __syncthreads();
    int run = part[t];
    for (int i = 0; i < per; ++i) { int idx = t * per + i; rs[idx] = run; run += cnt[idx]; }
}
__global__ void k_scatter(const int* __restrict__ gsrc, const int* __restrict__ gdst,
                          const int* __restrict__ rs, int* __restrict__ cur, int* __restrict__ csr) {
    int i = blockIdx.x * 256 + threadIdx.x;
    int d = gdst[i];
    int pos = atomicAdd(&cur[d], 1);
    csr[rs[d] + pos] = gsrc[i];
}
__global__ void k_temb(const float* __restrict__ t, const float* __restrict__ tw1,
                       const float* __restrict__ tb1, const float* __restrict__ tw2,
                       const float* __restrict__ tb2, float* __restrict__ temb) {
    __shared__ float t0[128];
    __shared__ float h1[64];
    int b = blockIdx.x, j = threadIdx.x;  // 64 threads
    float tv = t[b];
    float f = expf(-0.14391156831212787f * (float)j);
    float ang = tv * f;
    t0[j] = cosf(ang);
    t0[j + 64] = sinf(ang);
    __syncthreads();
    float s = tb1[j];
    for (int i = 0; i < 128; ++i) s = fmaf(t0[i], tw1[i * 64 + j], s);
    h1[j] = fmaxf(s, 0.f);
    __syncthreads();
    float s2 = tb2[j];
    for (int i = 0; i < 64; ++i) s2 = fmaf(h1[i], tw2[i * 64 + j], s2);
    temb[b * 64 + j] = s2;
}
__global__ void k_tg(const float* __restrict__ temb, const float* __restrict__ agT,
                     const float* __restrict__ agTb, float* __restrict__ tG) {
    __shared__ float tm[64];
    int bid = blockIdx.x;
    int l = bid >> 6, p = bid & 63, c = threadIdx.x;
    if (c < 64) tm[c] = temb[p * 64 + c];
    __syncthreads();
    const float* T = agT + (size_t)l * 64 * kH;
    float s = agTb[l * kH + c];
    for (int i = 0; i < 64; ++i) s = fmaf(tm[i], T[i * kH + c], s);
    tG[((size_t)l * 64 + p) * kH + c] = s;
}

extern "C" void kernel_launch(void* const* d_in, const int* in_sizes, int n_in,
                              void* d_out, int out_size, void* d_ws, size_t ws_size,
                              hipStream_t stream)
{
    (void)in_sizes; (void)n_in; (void)out_size; (void)ws_size;
    const float* graph_x = (const float*)d_in[0];
    const float* t_in    = (const float*)d_in[1];
    const float* attr    = (const float*)d_in[2];
    const int*   gedge   = (const int*)d_in[3];
    const float* gin_eps = (const float*)d_in[7];
    const float* gin_w1  = (const float*)d_in[8];
    const float* gin_b1  = (const float*)d_in[9];
    const float* gin_w2  = (const float*)d_in[10];
    const float* gin_b2  = (const float*)d_in[11];
    const float* gn_w    = (const float*)d_in[12];
    const float* gn_b    = (const float*)d_in[13];
    const float* gn_ms   = (const float*)d_in[14];
    const float* ag_U    = (const float*)d_in[15];
    const float* ag_Ub   = (const float*)d_in[16];
    const float* ag_V    = (const float*)d_in[17];
    const float* ag_Vb   = (const float*)d_in[18];
    const float* ag_A    = (const float*)d_in[19];
    const float* ag_Ab   = (const float*)d_in[20];
    const float* ag_B    = (const float*)d_in[21];
    const float* ag_Bb   = (const float*)d_in[22];
    const float* ag_C    = (const float*)d_in[23];
    const float* ag_Cb   = (const float*)d_in[24];
    const float* ag_T    = (const float*)d_in[25];
    const float* ag_Tb   = (const float*)d_in[26];
    const float* tw1     = (const float*)d_in[27];
    const float* tb1     = (const float*)d_in[28];
    const float* tw2     = (const float*)d_in[29];
    const float* tb2     = (const float*)d_in[30];
    const float* ew      = (const float*)d_in[31];
    const float* eb      = (const float*)d_in[32];
    const float* mw1     = (const float*)d_in[33];
    const float* mb1     = (const float*)d_in[34];
    const float* mw2     = (const float*)d_in[35];
    const float* mb2     = (const float*)d_in[36];
    const float* mw3     = (const float*)d_in[37];
    const float* mb3     = (const float*)d_in[38];
    float* out = (float*)d_out;

    char* wsb = (char*)d_ws;
    size_t o = 0;
    auto carve = [&](size_t bytes) { char* p = wsb + o; o += (bytes + 255) & ~(size_t)255; return p; };
    uint32_t* e_packed    = (uint32_t*)carve((size_t)kE2 * kH * 4);
    unsigned short* gate  = (unsigned short*)carve((size_t)kE2 * kH * 2);
    float* h              = (float*)carve((size_t)kN * kH * 4);
    float* hB             = (float*)carve((size_t)kN * kH * 4);
    float* hC             = (float*)carve((size_t)kN * kH * 4);
    float* hV             = (float*)carve((size_t)kN * kH * 4);
    float* hU             = (float*)carve((size_t)kN * kH * 4);
    float* temb           = (float*)carve((size_t)kB * kHT * 4);
    float* tG             = (float*)carve((size_t)kL * kB * kH * 4);
    int* cnt              = (int*)carve((size_t)kN * 4);
    int* cur              = (int*)carve((size_t)kN * 4);
    int* rs               = (int*)carve((size_t)(kN + 1) * 4);
    int* csr              = (int*)carve((size_t)kEG * 4);
    unsigned short* wf_all = (unsigned short*)carve((size_t)22 * 16384 * 2);
    unsigned short* wf_m1 = (unsigned short*)carve((size_t)kH * 256 * 2);
    unsigned short* wf_m2 = (unsigned short*)carve((size_t)256 * kH * 2);

    const int* gsrc = gedge;
    const int* gdst = gedge + kEG;

    hipMemsetAsync(cnt, 0, (size_t)kN * 4, stream);
    hipMemsetAsync(cur, 0, (size_t)kN * 4, stream);
    hipMemcpyAsync(h, graph_x, (size_t)kN * kH * 4, hipMemcpyDeviceToDevice, stream);

    k_hist<<<kEG / 256, 256, 0, stream>>>(gdst, cnt);
    k_scan<<<1, 256, 0, stream>>>(cnt, rs);
    k_scatter<<<kEG / 256, 256, 0, stream>>>(gsrc, gdst, rs, cur, csr);
    k_temb<<<kB, 64, 0, stream>>>(t_in, tw1, tb1, tw2, tb2, temb);
    k_tg<<<kL * kB, kH, 0, stream>>>(temb, ag_T, ag_Tb, tG);

    // weight prep
    {
        WSrcs s;
        s.p[0] = ew;
        for (int l = 0; l < 3; ++l) {
            s.p[1 + l]  = ag_A   + (size_t)l * kH * kH;
            s.p[4 + l]  = gin_w1 + (size_t)l * kH * kH;
            s.p[7 + l]  = gin_w2 + (size_t)l * kH * kH;
            s.p[10 + l] = ag_B   + (size_t)l * kH * kH;
            s.p[13 + l] = ag_C   + (size_t)l * kH * kH;
            s.p[16 + l] = ag_V   + (size_t)l * kH * kH;
            s.p[19 + l] = ag_U   + (size_t)l * kH * kH;
        }
        k_wprep_multi<<<22 * 32, 64, 0, stream>>>(s, wf_all);
    }
    k_wprep<<<4 * 16, 64, 0, stream>>>(mw1, wf_m1, 256);
    k_wprep<<<8 * 8, 64, 0, stream>>>(mw2, wf_m2, kH);

    // PE gemm: halves identical -> grid over first half only, dual store
    k_pegemm<<<kE / 64, 256, 0, stream>>>(attr, wf_all /*ew frags*/, eb, e_packed);

    auto wf = [&](int idx) { return wf_all + (size_t)idx * 16384; };
    for (int l = 0; l < kL; ++l) {
        k_node<<<128, 256, 0, stream>>>(
            h, l, rs, csr, gin_eps,
            wf(4 + l), gin_b1 + (size_t)l * kH,
            wf(7 + l), gin_b2 + (size_t)l * kH,
            gn_w + (size_t)l * kH, gn_b + (size_t)l * kH, gn_ms + (size_t)l * kH,
            wf(10 + l), ag_Bb + (size_t)l * kH,
            wf(13 + l), ag_Cb + (size_t)l * kH,
            wf(16 + l), ag_Vb + (size_t)l * kH,
            wf(19 + l), ag_Ub + (size_t)l * kH,
            hB, hC, hV, hU);
        if (l < kL - 1) {
            k_egemm<true><<<kE2 / 128, 256, 0, stream>>>(
                e_packed, wf(1 + l), ag_Ab + (size_t)l * kH, tG + (size_t)l * kB * kH,
                hB, hC, gate);
            k_agg<<<kN, kH, 0, stream>>>(gate, hV, hU, h);
        } else {
            k_egemm<false><<<kE2 / 128, 256, 0, stream>>>(
                e_packed, wf(1 + l), ag_Ab + (size_t)l * kH, tG + (size_t)l * kB * kH,
                hB, hC, gate);
        }
    }

    k_readout2<<<kE / 64, 256, 0, stream>>>(e_packed, wf_m1, mb1, wf_m2, mb2, mw3, mb3, out);
}

// Round 13
// 952.215 us; speedup vs baseline: 1.0241x; 1.0241x over previous
//
#include <hip/hip_runtime.h>
#include <cstdint>
#include <cstddef>

constexpr int kB   = 64;
constexpr int kNPG = 48;
constexpr int kN   = 6144;
constexpr int kE   = 147456;
constexpr int kE2  = 294912;
constexpr int kEG  = 98304;
constexpr int kH   = 128;
constexpr int kHT  = 64;
constexpr int kL   = 3;

using short8 = __attribute__((ext_vector_type(8))) short;
using f32x4  = __attribute__((ext_vector_type(4))) float;

__device__ __forceinline__ unsigned short f2bf(float x) {
    unsigned int u = __float_as_uint(x);
    u = (u + 0x7FFFu + ((u >> 16) & 1u)) >> 16;   // RNE
    return (unsigned short)u;
}
__device__ __forceinline__ float bf2f(unsigned short v) {
    return __uint_as_float(((unsigned int)v) << 16);
}
// split-bf16 pack: hi = truncated top-16, lo = RNE(residual).
__device__ __forceinline__ uint32_t packsplit(float v) {
    unsigned int u = __float_as_uint(v);
    unsigned int hi = u >> 16;
    float vhi = __uint_as_float(u & 0xffff0000u);
    unsigned short lo = f2bf(v - vhi);
    return hi | ((uint32_t)lo << 16);
}
__device__ __forceinline__ f32x4 mfma16(short8 a, short8 b, f32x4 c) {
    return __builtin_amdgcn_mfma_f32_16x16x32_bf16(a, b, c, 0, 0, 0);
}
__device__ __forceinline__ void loadfrag(const uint32_t* p, short8& hi, short8& lo) {
    uint4 q0 = *(const uint4*)p;
    uint4 q1 = *(const uint4*)(p + 4);
    uint32_t qs[8] = {q0.x, q0.y, q0.z, q0.w, q1.x, q1.y, q1.z, q1.w};
    #pragma unroll
    for (int j = 0; j < 8; ++j) { hi[j] = (short)(qs[j] & 0xffff); lo[j] = (short)(qs[j] >> 16); }
}

// ---------------- weight prep: f32 [K][N] -> bf16 MFMA-B-fragment order ----------
__global__ void k_wprep(const float* __restrict__ W, unsigned short* __restrict__ Wf, int N) {
    int lane = threadIdx.x;                 // 64
    int NT = N >> 4;
    int kt = blockIdx.x / NT, nt = blockIdx.x % NT;
    int k0 = kt * 32 + (lane >> 4) * 8;
    int col = nt * 16 + (lane & 15);
    unsigned short tmp[8];
    #pragma unroll
    for (int j = 0; j < 8; ++j) tmp[j] = f2bf(W[(size_t)(k0 + j) * N + col]);
    unsigned short* dst = Wf + (((size_t)blockIdx.x) * 64 + lane) * 8;
    *(uint4*)dst = *(const uint4*)tmp;
}

struct WSrcs { const float* p[22]; };
__global__ void k_wprep_multi(WSrcs s, unsigned short* __restrict__ Wf) {
    int lane = threadIdx.x;
    int mat = blockIdx.x >> 5, tile = blockIdx.x & 31;
    int kt = tile >> 3, nt = tile & 7;
    const float* W = s.p[mat];
    int k0 = kt * 32 + (lane >> 4) * 8;
    int col = nt * 16 + (lane & 15);
    unsigned short tmp[8];
    #pragma unroll
    for (int j = 0; j < 8; ++j) tmp[j] = f2bf(W[(size_t)(k0 + j) * kH + col]);
    unsigned short* dst = Wf + (size_t)mat * 16384 + (((size_t)tile) * 64 + lane) * 8;
    *(uint4*)dst = *(const uint4*)tmp;
}

// ---------------- PE gemm: e0 = PE(attr) @ ew + eb. Rows j and kE+j identical ---
__global__ __launch_bounds__(256) void k_pegemm(const float* __restrict__ attr,
                                                const unsigned short* __restrict__ wf,
                                                const float* __restrict__ eb,
                                                uint32_t* __restrict__ e_packed) {
    int t = threadIdx.x, lane = t & 63, w = t >> 6;
    int rowbase = blockIdx.x * 64 + w * 16;       // < kE
    float av = attr[rowbase + (lane & 15)];
    f32x4 acc[8];
    #pragma unroll
    for (int nt = 0; nt < 8; ++nt) acc[nt] = (f32x4){0.f, 0.f, 0.f, 0.f};
    #pragma unroll
    for (int kt = 0; kt < 4; ++kt) {
        short8 ahi, alo;
        int k0 = kt * 32 + (lane >> 4) * 8;
        #pragma unroll
        for (int j = 0; j < 8; ++j) {
            int k = k0 + j;
            float freq = exp2f(-(float)(k >> 1) * 0.20762050593046264f); // 2*log2(1e4)/128
            float ang = av * freq;
            float v = (k & 1) ? __cosf(ang) : __sinf(ang);
            unsigned short h = f2bf(v);
            unsigned short l2 = f2bf(v - bf2f(h));
            ahi[j] = (short)h; alo[j] = (short)l2;
        }
        #pragma unroll
        for (int nt = 0; nt < 8; ++nt) {
            short8 wb = *(const short8*)&wf[(((size_t)kt * 8 + nt) * 64 + lane) * 8];
            acc[nt] = mfma16(ahi, wb, acc[nt]);
            acc[nt] = mfma16(alo, wb, acc[nt]);
        }
    }
    #pragma unroll
    for (int nt = 0; nt < 8; ++nt) {
        int col = nt * 16 + (lane & 15);
        float bb = eb[col];
        #pragma unroll
        for (int reg = 0; reg < 4; ++reg) {
            int row = rowbase + (lane >> 4) * 4 + reg;
            uint32_t pk = packsplit(acc[nt][reg] + bb);
            e_packed[(size_t)row * kH + col] = pk;
            e_packed[(size_t)(row + kE) * kH + col] = pk;
        }
    }
}

// ---------------- fused node kernel: gin -> MLP -> GraphNorm -> 4 projections ----
__global__ __launch_bounds__(256) void k_node(
    float* __restrict__ h,
    int l, const int* __restrict__ rs, const int* __restrict__ csr,
    const float* __restrict__ gin_eps,
    const unsigned short* __restrict__ wf_g1, const float* __restrict__ b1,
    const unsigned short* __restrict__ wf_g2, const float* __restrict__ b2,
    const float* __restrict__ gnw, const float* __restrict__ gnb, const float* __restrict__ gnms,
    const unsigned short* __restrict__ wf_B, const float* __restrict__ Bb,
    const unsigned short* __restrict__ wf_C, const float* __restrict__ Cb,
    const unsigned short* __restrict__ wf_V, const float* __restrict__ Vb,
    const unsigned short* __restrict__ wf_U, const float* __restrict__ Ub,
    float* __restrict__ hB, float* __restrict__ hC, float* __restrict__ hV, float* __restrict__ hU)
{
    __shared__ char sA[48 * 132 * 4];   // hS (f32) -> m1pk (u32) -> hnpk (u32)
    __shared__ char sB[48 * 132 * 4];   // zpk (u32) -> z2S (f32)
    __shared__ float mmS[128], aS[128], red0[128], red1[128];
    float    (*hS)[132]   = (float(*)[132])sA;
    uint32_t (*m1pk)[132] = (uint32_t(*)[132])sA;
    uint32_t (*hnpk)[132] = (uint32_t(*)[132])sA;
    uint32_t (*zpk)[132]  = (uint32_t(*)[132])sB;
    float    (*z2S)[132]  = (float(*)[132])sB;
    int t = threadIdx.x, lane = t & 63, w = t >> 6;
    int g = blockIdx.x, nbase = g * 48;

    // P0: load h
    for (int i = t; i < 48 * 128; i += 256) {
        int r = i >> 7, c = i & 127;
        hS[r][c] = h[(size_t)(nbase + r) * kH + c];
    }
    __syncthreads();

    // P1: GIN gather z = (1+eps)h + sum_neigh h  (neighbors are block-local)
    {
        float eps1 = 1.f + gin_eps[l];
        int c = t & 127;
        for (int rp = t >> 7; rp < 48; rp += 2) {
            float acc = eps1 * hS[rp][c];
            int s0 = rs[nbase + rp], s1 = rs[nbase + rp + 1];
            for (int k = s0; k < s1; ++k) {
                int s = csr[k] - nbase;
                acc += hS[s][c];
            }
            zpk[rp][c] = packsplit(acc);
        }
    }
    __syncthreads();

    // P2: GEMM1 z@W1 -> relu -> m1 (split-bf16, alias sA)
    {
        f32x4 acc1[8];
        if (w < 3) {
            #pragma unroll
            for (int nt = 0; nt < 8; ++nt) acc1[nt] = (f32x4){0.f, 0.f, 0.f, 0.f};
            #pragma unroll
            for (int kt = 0; kt < 4; ++kt) {
                short8 hi, lo;
                loadfrag(&zpk[w * 16 + (lane & 15)][kt * 32 + (lane >> 4) * 8], hi, lo);
                #pragma unroll
                for (int nt = 0; nt < 8; ++nt) {
                    short8 wb = *(const short8*)&wf_g1[(((size_t)kt * 8 + nt) * 64 + lane) * 8];
                    acc1[nt] = mfma16(hi, wb, acc1[nt]);
                    acc1[nt] = mfma16(lo, wb, acc1[nt]);
                }
            }
        }
        __syncthreads();   // hS dead -> safe to write m1pk
        if (w < 3) {
            #pragma unroll
            for (int nt = 0; nt < 8; ++nt) {
                int col = nt * 16 + (lane & 15);
                float bb = b1[col];
                #pragma unroll
                for (int reg = 0; reg < 4; ++reg) {
                    int row = w * 16 + (lane >> 4) * 4 + reg;
                    m1pk[row][col] = packsplit(fmaxf(acc1[nt][reg] + bb, 0.f));
                }
            }
        }
    }
    __syncthreads();

    // P3: GEMM2 m1@W2 -> z2 (f32, alias sB)
    {
        f32x4 acc2[8];
        if (w < 3) {
            #pragma unroll
            for (int nt = 0; nt < 8; ++nt) acc2[nt] = (f32x4){0.f, 0.f, 0.f, 0.f};
            #pragma unroll
            for (int kt = 0; kt < 4; ++kt) {
                short8 hi, lo;
                loadfrag(&m1pk[w * 16 + (lane & 15)][kt * 32 + (lane >> 4) * 8], hi, lo);
                #pragma unroll
                for (int nt = 0; nt < 8; ++nt) {
                    short8 wb = *(const short8*)&wf_g2[(((size_t)kt * 8 + nt) * 64 + lane) * 8];
                    acc2[nt] = mfma16(hi, wb, acc2[nt]);
                    acc2[nt] = mfma16(lo, wb, acc2[nt]);
                }
            }
        }
        __syncthreads();   // zpk dead
        if (w < 3) {
            #pragma unroll
            for (int nt = 0; nt < 8; ++nt) {
                int col = nt * 16 + (lane & 15);
                float bb = b2[col];
                #pragma unroll
                for (int reg = 0; reg < 4; ++reg) {
                    int row = w * 16 + (lane >> 4) * 4 + reg;
                    z2S[row][col] = acc2[nt][reg] + bb;
                }
            }
        }
    }
    __syncthreads();

    // P4: GraphNorm stats over the 48 rows
    {
        int c = t & 127, hh = t >> 7;
        float s = 0.f;
        for (int r = hh * 24; r < hh * 24 + 24; ++r) s += z2S[r][c];
        if (hh == 0) red0[c] = s; else red1[c] = s;
        __syncthreads();
        if (t < 128) {
            float mean = (red0[t] + red1[t]) * (1.f / 48.f);
            mmS[t] = mean * gnms[t];
        }
        __syncthreads();
        float mm = mmS[c];
        float s2 = 0.f;
        for (int r = hh * 24; r < hh * 24 + 24; ++r) { float d = z2S[r][c] - mm; s2 = fmaf(d, d, s2); }
        if (hh == 0) red0[c] = s2; else red1[c] = s2;
        __syncthreads();
        if (t < 128) {
            float var = (red0[t] + red1[t]) * (1.f / 48.f);
            aS[t] = gnw[t] * rsqrtf(var + 1e-5f);
        }
    }
    __syncthreads();

    // P5: h_new = relu(a*(z2-mm)+gnb) -> global h + split-bf16 pack (alias sA)
    for (int i = t; i < 48 * 128; i += 256) {
        int r = i >> 7, c = i & 127;
        float hn = fmaxf(aS[c] * (z2S[r][c] - mmS[c]) + gnb[c], 0.f);
        h[(size_t)(nbase + r) * kH + c] = hn;
        hnpk[r][c] = packsplit(hn);
    }
    __syncthreads();

    // P6: projections hB,hC,hV,hU = h_new @ {B,C,V,U} + bias
    {
        const unsigned short* wfs[4] = {wf_B, wf_C, wf_V, wf_U};
        const float* bs[4] = {Bb, Cb, Vb, Ub};
        float* outs[4] = {hB, hC, hV, hU};
        #pragma unroll 4
        for (int m = 0; m < 4; ++m) {
            if (w < 3) {
                f32x4 accp[8];
                #pragma unroll
                for (int nt = 0; nt < 8; ++nt) accp[nt] = (f32x4){0.f, 0.f, 0.f, 0.f};
                #pragma unroll
                for (int kt = 0; kt < 4; ++kt) {
                    short8 hi, lo;
                    loadfrag(&hnpk[w * 16 + (lane & 15)][kt * 32 + (lane >> 4) * 8], hi, lo);
                    #pragma unroll
                    for (int nt = 0; nt < 8; ++nt) {
                        short8 wb = *(const short8*)&wfs[m][(((size_t)kt * 8 + nt) * 64 + lane) * 8];
                        accp[nt] = mfma16(hi, wb, accp[nt]);
                        accp[nt] = mfma16(lo, wb, accp[nt]);
                    }
                }
                #pragma unroll
                for (int nt = 0; nt < 8; ++nt) {
                    int col = nt * 16 + (lane & 15);
                    float bb = bs[m][col];
                    #pragma unroll
                    for (int reg = 0; reg < 4; ++reg) {
                        int row = w * 16 + (lane >> 4) * 4 + reg;
                        outs[m][(size_t)(nbase + row) * kH + col] = accp[nt][reg] + bb;
                    }
                }
            }
        }
    }
}

// ---------------- AGNN edge gemm (padded LDS, gate store templated) --------------
template<bool GATE>
__global__ __launch_bounds__(256) void k_egemm(uint32_t* __restrict__ e_packed,
                                               const unsigned short* __restrict__ wfA,
                                               const float* __restrict__ Ab,
                                               const float* __restrict__ tGl,
                                               const float* __restrict__ hB,
                                               const float* __restrict__ hC,
                                               unsigned short* __restrict__ gate) {
    __shared__ float X[48][132];   // b-side node rows (+4 pad)
    __shared__ float Y[4][132];    // a-side node rows
    __shared__ float Z[128];       // tG[p] + Ab
    int t = threadIdx.x, lane = t & 63, w = t >> 6;
    int row0 = blockIdx.x * 128;
    int half = row0 >= kE;
    int off = row0 - (half ? kE : 0);
    int p = off / 2304;
    int off2 = off - p * 2304;
    int a0 = off2 / 48, boff = off2 - a0 * 48;
    const float* Xsrc = half ? hB : hC;
    const float* Ysrc = half ? hC : hB;

    if (t < 128) Z[t] = tGl[p * kH + t] + Ab[t];
    for (int i = t; i < 48 * 32; i += 256) {
        int r = i >> 5, c = (i & 31) << 2;
        *(float4*)&X[r][c] = *(const float4*)&Xsrc[(size_t)(p * 96 + 48 + r) * kH + c];
    }
    for (int i = t; i < 4 * 32; i += 256) {
        int r = i >> 5, c = (i & 31) << 2;
        int a = a0 + r; if (a > 47) a = 47;
        *(float4*)&Y[r][c] = *(const float4*)&Ysrc[(size_t)(p * 96 + a) * kH + c];
    }
    __syncthreads();

    f32x4 acc[2][8];
    #pragma unroll
    for (int rt = 0; rt < 2; ++rt)
        #pragma unroll
        for (int nt = 0; nt < 8; ++nt) acc[rt][nt] = (f32x4){0.f, 0.f, 0.f, 0.f};

    #pragma unroll
    for (int kt = 0; kt < 4; ++kt) {
        short8 hi[2], lo[2];
        #pragma unroll
        for (int rt = 0; rt < 2; ++rt) {
            int row = row0 + w * 32 + rt * 16 + (lane & 15);
            loadfrag(e_packed + (size_t)row * kH + kt * 32 + (lane >> 4) * 8, hi[rt], lo[rt]);
        }
        #pragma unroll
        for (int nt = 0; nt < 8; ++nt) {
            short8 wb = *(const short8*)&wfA[(((size_t)kt * 8 + nt) * 64 + lane) * 8];
            #pragma unroll
            for (int rt = 0; rt < 2; ++rt) {
                acc[rt][nt] = mfma16(hi[rt], wb, acc[rt][nt]);
                acc[rt][nt] = mfma16(lo[rt], wb, acc[rt][nt]);
            }
        }
    }

    #pragma unroll
    for (int rt = 0; rt < 2; ++rt) {
        #pragma unroll
        for (int nt = 0; nt < 8; ++nt) {
            int col = nt * 16 + (lane & 15);
            float zc = Z[col];
            #pragma unroll
            for (int reg = 0; reg < 4; ++reg) {
                int rl = w * 32 + rt * 16 + (lane >> 4) * 4 + reg;   // 0..127
                int idx2 = boff + rl;
                int arel = (idx2 >= 144) ? 3 : (idx2 >= 96) ? 2 : (idx2 >= 48) ? 1 : 0;
                int b = idx2 - arel * 48;
                float v = acc[rt][nt][reg] + zc + Y[arel][col] + X[b][col];
                int grow = row0 + rl;
                if (GATE) {
                    float g = 1.f / (1.f + __expf(-v));
                    gate[(size_t)grow * kH + col] = f2bf(g);
                }
                uint32_t old = e_packed[(size_t)grow * kH + col];
                float ne = bf2f((unsigned short)(old & 0xffff)) + bf2f((unsigned short)(old >> 16))
                           + fmaxf(v, 0.f);
                e_packed[(size_t)grow * kH + col] = packsplit(ne);
            }
        }
    }
}

// ---------------- dense gated aggregation + node update (validated) --------------
__global__ void k_agg(const unsigned short* __restrict__ gate, const float* __restrict__ hV,
                      const float* __restrict__ hU, float* __restrict__ h) {
    int n = blockIdx.x, c = threadIdx.x;
    int p = n / 96, r = n - (n / 96) * 96;
    float acc = 0.f;
    if (r >= 48) {
        int b = r - 48;
        size_t ebase = (size_t)p * 2304 + b;
        for (int a = 0; a < 48; ++a) {
            size_t eidx = ebase + (size_t)a * 48;
            int src = p * 96 + a;
            acc = fmaf(bf2f(gate[eidx * kH + c]), hV[(size_t)src * kH + c], acc);
        }
    } else {
        int a = r;
        size_t ebase = (size_t)kE + (size_t)p * 2304 + (size_t)a * 48;
        for (int b = 0; b < 48; ++b) {
            int src = p * 96 + 48 + b;
            acc = fmaf(bf2f(gate[(ebase + b) * kH + c]), hV[(size_t)src * kH + c], acc);
        }
    }
    float v = hU[(size_t)n * kH + c] + acc;
    h[(size_t)n * kH + c] += fmaxf(v, 0.f);
}

// ---------------- fused readout (validated round-8 split form) -------------------
__global__ __launch_bounds__(256) void k_readout(const uint32_t* __restrict__ e_packed,
                                                 const unsigned short* __restrict__ wf1,
                                                 const float* __restrict__ mb1,
                                                 const unsigned short* __restrict__ wf2,
                                                 const float* __restrict__ mb2,
                                                 const float* __restrict__ mw3,
                                                 const float* __restrict__ mb3,
                                                 float* __restrict__ partial) {
    __shared__ char smem[64 * 528];   // aliased: eS[64][132] u32  /  m1S[64][264] bf16
    uint32_t (*eS)[132] = (uint32_t(*)[132])smem;
    unsigned short (*m1S)[264] = (unsigned short(*)[264])smem;
    int t = threadIdx.x, lane = t & 63, w = t >> 6;
    int row0 = blockIdx.x * 64;

    for (int i = t; i < 64 * 32; i += 256) {
        int r = i >> 5, c = (i & 31) << 2;
        *(uint4*)&eS[r][c] = *(const uint4*)&e_packed[(size_t)(row0 + r) * kH + c];
    }
    __syncthreads();

    f32x4 acc1[4][4];
    #pragma unroll
    for (int rt = 0; rt < 4; ++rt)
        #pragma unroll
        for (int n = 0; n < 4; ++n) acc1[rt][n] = (f32x4){0.f, 0.f, 0.f, 0.f};
    #pragma unroll
    for (int kt = 0; kt < 4; ++kt) {
        short8 ahi[4], alo[4];
        #pragma unroll
        for (int rt = 0; rt < 4; ++rt)
            loadfrag(&eS[rt * 16 + (lane & 15)][kt * 32 + (lane >> 4) * 8], ahi[rt], alo[rt]);
        #pragma unroll
        for (int n = 0; n < 4; ++n) {
            int nt = w * 4 + n;
            short8 wb = *(const short8*)&wf1[(((size_t)kt * 16 + nt) * 64 + lane) * 8];
            #pragma unroll
            for (int rt = 0; rt < 4; ++rt) {
                acc1[rt][n] = mfma16(ahi[rt], wb, acc1[rt][n]);
                acc1[rt][n] = mfma16(alo[rt], wb, acc1[rt][n]);
            }
        }
    }
    __syncthreads();
    #pragma unroll
    for (int rt = 0; rt < 4; ++rt) {
        #pragma unroll
        for (int n = 0; n < 4; ++n) {
            int col = (w * 4 + n) * 16 + (lane & 15);
            float bb = mb1[col];
            #pragma unroll
            for (int reg = 0; reg < 4; ++reg) {
                int r = rt * 16 + (lane >> 4) * 4 + reg;
                m1S[r][col] = f2bf(fmaxf(acc1[rt][n][reg] + bb, 0.f));
            }
        }
    }
    __syncthreads();

    f32x4 acc2[8];
    #pragma unroll
    for (int nt = 0; nt < 8; ++nt) acc2[nt] = (f32x4){0.f, 0.f, 0.f, 0.f};
    #pragma unroll
    for (int kt = 0; kt < 8; ++kt) {
        int r = w * 16 + (lane & 15);
        short8 a2 = *(const short8*)&m1S[r][kt * 32 + (lane >> 4) * 8];
        #pragma unroll
        for (int nt = 0; nt < 8; ++nt) {
            short8 wb = *(const short8*)&wf2[(((size_t)kt * 8 + nt) * 64 + lane) * 8];
            acc2[nt] = mfma16(a2, wb, acc2[nt]);
        }
    }
    float s[4] = {0.f, 0.f, 0.f, 0.f};
    #pragma unroll
    for (int nt = 0; nt < 8; ++nt) {
        int col = nt * 16 + (lane & 15);
        float w3 = mw3[col], bb = mb2[col];
        #pragma unroll
        for (int reg = 0; reg < 4; ++reg)
            s[reg] += fmaxf(acc2[nt][reg] + bb, 0.f) * w3;
    }
    #pragma unroll
    for (int mask = 1; mask <= 8; mask <<= 1)
        #pragma unroll
        for (int reg = 0; reg < 4; ++reg) s[reg] += __shfl_xor(s[reg], mask);
    if ((lane & 15) == 0) {
        float b3 = mb3[0];
        #pragma unroll
        for (int reg = 0; reg < 4; ++reg)
            partial[row0 + w * 16 + (lane >> 4) * 4 + reg] = s[reg] + b3;
    }
}

__global__ void k_final(const float* __restrict__ partial, float* __restrict__ out) {
    int i = blockIdx.x * 256 + threadIdx.x;
    out[i] = partial[i] + partial[i + kE];
}

// ---------------- graph-structure + small kernels (validated) --------------------
__global__ void k_hist(const int* __restrict__ gdst, int* __restrict__ cnt) {
    int i = blockIdx.x * 256 + threadIdx.x;
    atomicAdd(&cnt[gdst[i]], 1);
}
__global__ void k_scan(const int* __restrict__ cnt, int* __restrict__ rs) {
    __shared__ int part[256];
    int t = threadIdx.x;
    const int per = kN / 256;
    int s = 0;
    for (int i = 0; i < per; ++i) s += cnt[t * per + i];
    part[t] = s;
    __syncthreads();
    if (t == 0) {
        int run = 0;
        for (int i = 0; i < 256; ++i) { int v = part[i]; part[i] = run; run += v; }
        rs[kN] = run;
    }
    __syncthreads();
    int run = part[t];
    for (int i = 0; i < per; ++i) { int idx = t * per + i; rs[idx] = run; run += cnt[idx]; }
}
__global__ void k_scatter(const int* __restrict__ gsrc, const int* __restrict__ gdst,
                          const int* __restrict__ rs, int* __restrict__ cur, int* __restrict__ csr) {
    int i = blockIdx.x * 256 + threadIdx.x;
    int d = gdst[i];
    int pos = atomicAdd(&cur[d], 1);
    csr[rs[d] + pos] = gsrc[i];
}
__global__ void k_temb(const float* __restrict__ t, const float* __restrict__ tw1,
                       const float* __restrict__ tb1, const float* __restrict__ tw2,
                       const float* __restrict__ tb2, float* __restrict__ temb) {
    __shared__ float t0[128];
    __shared__ float h1[64];
    int b = blockIdx.x, j = threadIdx.x;  // 64 threads
    float tv = t[b];
    float f = expf(-0.14391156831212787f * (float)j);
    float ang = tv * f;
    t0[j] = cosf(ang);
    t0[j + 64] = sinf(ang);
    __syncthreads();
    float s = tb1[j];
    for (int i = 0; i < 128; ++i) s = fmaf(t0[i], tw1[i * 64 + j], s);
    h1[j] = fmaxf(s, 0.f);
    __syncthreads();
    float s2 = tb2[j];
    for (int i = 0; i < 64; ++i) s2 = fmaf(h1[i], tw2[i * 64 + j], s2);
    temb[b * 64 + j] = s2;
}
__global__ void k_tg(const float* __restrict__ temb, const float* __restrict__ agT,
                     const float* __restrict__ agTb, float* __restrict__ tG) {
    __shared__ float tm[64];
    int bid = blockIdx.x;
    int l = bid >> 6, p = bid & 63, c = threadIdx.x;
    if (c < 64) tm[c] = temb[p * 64 + c];
    __syncthreads();
    const float* T = agT + (size_t)l * 64 * kH;
    float s = agTb[l * kH + c];
    for (int i = 0; i < 64; ++i) s = fmaf(tm[i], T[i * kH + c], s);
    tG[((size_t)l * 64 + p) * kH + c] = s;
}

extern "C" void kernel_launch(void* const* d_in, const int* in_sizes, int n_in,
                              void* d_out, int out_size, void* d_ws, size_t ws_size,
                              hipStream_t stream)
{
    (void)in_sizes; (void)n_in; (void)out_size; (void)ws_size;
    const float* graph_x = (const float*)d_in[0];
    const float* t_in    = (const float*)d_in[1];
    const float* attr    = (const float*)d_in[2];
    const int*   gedge   = (const int*)d_in[3];
    const float* gin_eps = (const float*)d_in[7];
    const float* gin_w1  = (const float*)d_in[8];
    const float* gin_b1  = (const float*)d_in[9];
    const float* gin_w2  = (const float*)d_in[10];
    const float* gin_b2  = (const float*)d_in[11];
    const float* gn_w    = (const float*)d_in[12];
    const float* gn_b    = (const float*)d_in[13];
    const float* gn_ms   = (const float*)d_in[14];
    const float* ag_U    = (const float*)d_in[15];
    const float* ag_Ub   = (const float*)d_in[16];
    const float* ag_V    = (const float*)d_in[17];
    const float* ag_Vb   = (const float*)d_in[18];
    const float* ag_A    = (const float*)d_in[19];
    const float* ag_Ab   = (const float*)d_in[20];
    const float* ag_B    = (const float*)d_in[21];
    const float* ag_Bb   = (const float*)d_in[22];
    const float* ag_C    = (const float*)d_in[23];
    const float* ag_Cb   = (const float*)d_in[24];
    const float* ag_T    = (const float*)d_in[25];
    const float* ag_Tb   = (const float*)d_in[26];
    const float* tw1     = (const float*)d_in[27];
    const float* tb1     = (const float*)d_in[28];
    const float* tw2     = (const float*)d_in[29];
    const float* tb2     = (const float*)d_in[30];
    const float* ew      = (const float*)d_in[31];
    const float* eb      = (const float*)d_in[32];
    const float* mw1     = (const float*)d_in[33];
    const float* mb1     = (const float*)d_in[34];
    const float* mw2     = (const float*)d_in[35];
    const float* mb2     = (const float*)d_in[36];
    const float* mw3     = (const float*)d_in[37];
    const float* mb3     = (const float*)d_in[38];
    float* out = (float*)d_out;

    char* wsb = (char*)d_ws;
    size_t o = 0;
    auto carve = [&](size_t bytes) { char* p = wsb + o; o += (bytes + 255) & ~(size_t)255; return p; };
    uint32_t* e_packed    = (uint32_t*)carve((size_t)kE2 * kH * 4);
    unsigned short* gate  = (unsigned short*)carve((size_t)kE2 * kH * 2);
    float* h              = (float*)carve((size_t)kN * kH * 4);
    float* hB             = (float*)carve((size_t)kN * kH * 4);
    float* hC             = (float*)carve((size_t)kN * kH * 4);
    float* hV             = (float*)carve((size_t)kN * kH * 4);
    float* hU             = (float*)carve((size_t)kN * kH * 4);
    float* temb           = (float*)carve((size_t)kB * kHT * 4);
    float* tG             = (float*)carve((size_t)kL * kB * kH * 4);
    float* partial        = (float*)carve((size_t)kE2 * 4);
    int* cnt              = (int*)carve((size_t)kN * 4);
    int* cur              = (int*)carve((size_t)kN * 4);
    int* rs               = (int*)carve((size_t)(kN + 1) * 4);
    int* csr              = (int*)carve((size_t)kEG * 4);
    unsigned short* wf_all = (unsigned short*)carve((size_t)22 * 16384 * 2);
    unsigned short* wf_m1 = (unsigned short*)carve((size_t)kH * 256 * 2);
    unsigned short* wf_m2 = (unsigned short*)carve((size_t)256 * kH * 2);

    const int* gsrc = gedge;
    const int* gdst = gedge + kEG;

    hipMemsetAsync(cnt, 0, (size_t)kN * 4, stream);
    hipMemsetAsync(cur, 0, (size_t)kN * 4, stream);
    hipMemcpyAsync(h, graph_x, (size_t)kN * kH * 4, hipMemcpyDeviceToDevice, stream);

    k_hist<<<kEG / 256, 256, 0, stream>>>(gdst, cnt);
    k_scan<<<1, 256, 0, stream>>>(cnt, rs);
    k_scatter<<<kEG / 256, 256, 0, stream>>>(gsrc, gdst, rs, cur, csr);
    k_temb<<<kB, 64, 0, stream>>>(t_in, tw1, tb1, tw2, tb2, temb);
    k_tg<<<kL * kB, kH, 0, stream>>>(temb, ag_T, ag_Tb, tG);

    // weight prep
    {
        WSrcs s;
        s.p[0] = ew;
        for (int l = 0; l < 3; ++l) {
            s.p[1 + l]  = ag_A   + (size_t)l * kH * kH;
            s.p[4 + l]  = gin_w1 + (size_t)l * kH * kH;
            s.p[7 + l]  = gin_w2 + (size_t)l * kH * kH;
            s.p[10 + l] = ag_B   + (size_t)l * kH * kH;
            s.p[13 + l] = ag_C   + (size_t)l * kH * kH;
            s.p[16 + l] = ag_V   + (size_t)l * kH * kH;
            s.p[19 + l] = ag_U   + (size_t)l * kH * kH;
        }
        k_wprep_multi<<<22 * 32, 64, 0, stream>>>(s, wf_all);
    }
    k_wprep<<<4 * 16, 64, 0, stream>>>(mw1, wf_m1, 256);
    k_wprep<<<8 * 8, 64, 0, stream>>>(mw2, wf_m2, kH);

    // PE gemm: halves identical -> grid over first half only, dual store
    k_pegemm<<<kE / 64, 256, 0, stream>>>(attr, wf_all /*ew frags*/, eb, e_packed);

    auto wf = [&](int idx) { return wf_all + (size_t)idx * 16384; };
    for (int l = 0; l < kL; ++l) {
        k_node<<<128, 256, 0, stream>>>(
            h, l, rs, csr, gin_eps,
            wf(4 + l), gin_b1 + (size_t)l * kH,
            wf(7 + l), gin_b2 + (size_t)l * kH,
            gn_w + (size_t)l * kH, gn_b + (size_t)l * kH, gn_ms + (size_t)l * kH,
            wf(10 + l), ag_Bb + (size_t)l * kH,
            wf(13 + l), ag_Cb + (size_t)l * kH,
            wf(16 + l), ag_Vb + (size_t)l * kH,
            wf(19 + l), ag_Ub + (size_t)l * kH,
            hB, hC, hV, hU);
        if (l < kL - 1) {
            k_egemm<true><<<kE2 / 128, 256, 0, stream>>>(
                e_packed, wf(1 + l), ag_Ab + (size_t)l * kH, tG + (size_t)l * kB * kH,
                hB, hC, gate);
            k_agg<<<kN, kH, 0, stream>>>(gate, hV, hU, h);
        } else {
            k_egemm<false><<<kE2 / 128, 256, 0, stream>>>(
                e_packed, wf(1 + l), ag_Ab + (size_t)l * kH, tG + (size_t)l * kB * kH,
                hB, hC, gate);
        }
    }

    k_readout<<<kE2 / 64, 256, 0, stream>>>(e_packed, wf_m1, mb1, wf_m2, mb2, mw3, mb3, partial);
    k_final<<<kE / 256, 256, 0, stream>>>(partial, out);
}